// Round 28
// baseline (169.809 us; speedup 1.0000x reference)
//
#include <hip/hip_runtime.h>
#include <stdint.h>

#define NB_TOK 8192   // B*N
#define DMODEL 768
#define NHEAD 12
#define HDIM 64
#define QKV3 2304
#define SEQ 2048
#define NBATCH 4
#define SCALE_F 0.125f
#define LOG2E 1.44269504f

typedef _Float16 f16;
typedef __attribute__((ext_vector_type(2))) __fp16 hf16x2;   // cvt_pkrtz return type
typedef __attribute__((ext_vector_type(4))) _Float16 f16x4;
typedef __attribute__((ext_vector_type(8))) _Float16 f16x8;
typedef __attribute__((ext_vector_type(4))) float f32x4;
typedef __attribute__((ext_vector_type(16))) float f32x16;

__device__ __forceinline__ void gload_lds16(const void* g, void* l) {
  __builtin_amdgcn_global_load_lds(
      (const __attribute__((address_space(1))) unsigned int*)g,
      (__attribute__((address_space(3))) unsigned int*)l, 16, 0, 0);
}

// bare v_exp_f32 via the intrinsic (R18-verified).
__device__ __forceinline__ float fast_exp2(float x) {
  return __builtin_amdgcn_exp2f(x);
}

// ---------------- converts ----------------
__global__ __launch_bounds__(256) void cvt_f32_f16_k(const float* __restrict__ in,
                                                     f16* __restrict__ out) {
  const int i = (blockIdx.x * 256 + threadIdx.x) * 4;
  const float4 v = *reinterpret_cast<const float4*>(in + i);
  f16x4 o;
  o[0] = (f16)v.x; o[1] = (f16)v.y; o[2] = (f16)v.z; o[3] = (f16)v.w;
  *reinterpret_cast<f16x4*>(out + i) = o;
}

// out[c][r] = in[r][c].  Linear over INPUT: reads coalesced (the loads a wave
// must wait on); writes scattered (stores are fire-and-forget). R27's version
// was output-linear -> 64-line gather per wave-load on the read side.
__global__ __launch_bounds__(256) void transpose_cvt_k(const float* __restrict__ in,
                                                       f16* __restrict__ out,
                                                       int R, int C) {
  const int idx = blockIdx.x * 256 + threadIdx.x;   // input index
  const int r = idx / C, c = idx - r * C;
  out[(size_t)c * R + r] = (f16)in[idx];
}

// --- 128x128 MFMA GEMM, BK=32, 4 waves, 2-DEEP pipeline + XCD swizzle ------
// R22-VERIFIED (session best). MODE 0 epilogue writes Q/K/V in MFMA-FRAGMENT
// layout; K PRE-SCALED by LOG2E so attention uses exp2 directly.
template <int MODE>
__global__ __launch_bounds__(256) void gemm128_k(
    const f16* __restrict__ A, const f16* __restrict__ Bt,
    const float* __restrict__ bias, int K,
    f16* __restrict__ Qf, f16* __restrict__ Kf, f16* __restrict__ Vf,
    float* __restrict__ Of) {
  __shared__ __align__(16) f16 As[3][128 * 32];
  __shared__ __align__(16) f16 Bs[3][128 * 32];
  const int tid = threadIdx.x;
  const int w = tid >> 6, l = tid & 63;
  const int lr = l >> 2, lc = l & 3;
  const int nwg = gridDim.x * gridDim.y;
  const int lid = blockIdx.y * gridDim.x + blockIdx.x;
  const int wg = (lid & 7) * (nwg >> 3) + (lid >> 3);
  const int bm = (wg / gridDim.x) * 128, bn = (wg % gridDim.x) * 128;
  const f16* ga = A + (size_t)(bm + lr) * K + lc * 8;
  const f16* gb = Bt + (size_t)(bn + lr) * K + lc * 8;
  const int wr = (w >> 1) * 64, wc = (w & 1) * 64;
  const int fr = l & 15, fk = (l >> 4) * 8;

  auto stage = [&](int bb, int kt) {
    gload_lds16(ga + (size_t)(w * 16) * K + kt, &As[bb][(w * 16) * 32]);
    gload_lds16(ga + (size_t)((w + 4) * 16) * K + kt, &As[bb][((w + 4) * 16) * 32]);
    gload_lds16(gb + (size_t)(w * 16) * K + kt, &Bs[bb][(w * 16) * 32]);
    gload_lds16(gb + (size_t)((w + 4) * 16) * K + kt, &Bs[bb][((w + 4) * 16) * 32]);
  };

  f32x4 acc[4][4] = {};
  stage(0, 0);
  if (32 < K) stage(1, 32);
  int cur = 0;
  for (int kt = 0; kt < K; kt += 32) {
    if (kt + 64 < K) stage((cur + 2) % 3, kt + 64);
    if (kt + 64 < K)      asm volatile("s_waitcnt vmcnt(8)" ::: "memory");
    else if (kt + 32 < K) asm volatile("s_waitcnt vmcnt(4)" ::: "memory");
    else                  asm volatile("s_waitcnt vmcnt(0)" ::: "memory");
    __builtin_amdgcn_s_barrier();
    f16x8 af[4], bfrag[4];
#pragma unroll
    for (int mi = 0; mi < 4; mi++)
      af[mi] = *reinterpret_cast<const f16x8*>(&As[cur][(wr + mi * 16 + fr) * 32 + fk]);
#pragma unroll
    for (int ni = 0; ni < 4; ni++)
      bfrag[ni] = *reinterpret_cast<const f16x8*>(&Bs[cur][(wc + ni * 16 + fr) * 32 + fk]);
#pragma unroll
    for (int mi = 0; mi < 4; mi++)
#pragma unroll
      for (int ni = 0; ni < 4; ni++)
        acc[mi][ni] = __builtin_amdgcn_mfma_f32_16x16x32_f16(af[mi], bfrag[ni],
                                                             acc[mi][ni], 0, 0, 0);
    __builtin_amdgcn_s_barrier();
    cur = (cur + 1) % 3;
  }
  const int rgrp = (l >> 4) * 4;
#pragma unroll
  for (int ni = 0; ni < 4; ni++) {
    const int j = bn + wc + ni * 16 + fr;
    const float bb = bias[j];
    if (MODE == 0) {
      const int s = j / DMODEL;            // 0=Q 1=K 2=V, uniform per block
      const int rem = j - s * DMODEL;
      const int h = rem >> 6, hd = rem & 63;
      f16* dqk = (s == 0) ? Qf : Kf;
      const float scale = (s == 1) ? LOG2E : 1.0f;   // K pre-scaled for exp2
#pragma unroll
      for (int mi = 0; mi < 4; mi++)
#pragma unroll
        for (int r = 0; r < 4; r++) {
          const int m = bm + wr + mi * 16 + rgrp + r;   // global token
          const int bidx = m >> 11, n2 = m & 2047;      // batch, token-in-seq
          const f16 hv = (f16)((acc[mi][ni][r] + bb) * scale);
          const size_t bbase = (size_t)(bidx * NHEAD + h) * (SEQ * HDIM);
          if (s < 2) {
            const int mc = n2 >> 5, kt = hd >> 4;
            const int lane = (n2 & 31) + ((hd >> 3) & 1) * 32;
            dqk[bbase + (size_t)(((mc * 4 + kt) << 9) + (lane << 3) + (hd & 7))] = hv;
          } else {
            const int mc16 = n2 >> 4, g = hd >> 5;
            const int lane = (hd & 31) + ((n2 >> 3) & 1) * 32;
            Vf[bbase + (size_t)((((mc16 << 1) + g) << 9) + (lane << 3) + (n2 & 7))] = hv;
          }
        }
    } else {
#pragma unroll
      for (int mi = 0; mi < 4; mi++)
#pragma unroll
        for (int r = 0; r < 4; r++) {
          const int m = bm + wr + mi * 16 + rgrp + r;
          Of[(size_t)m * DMODEL + j] = acc[mi][ni][r] + bb;
        }
    }
  }
}

// ---------------- fused attention: LDS-staged shared K/V fragments ----------
// R22-VERIFIED. Three independent attn-structure modifications (R15 dacc,
// R24 tri-buffer, R26 dual-set) each failed correctness despite paper-proofs;
// this exact structure is the keeper.
__device__ __forceinline__ void attn_step(const f16x8 (&fk)[4], const f16x8 (&fv)[4],
                                          const f16x8 (&fq)[4], f32x16& o0, f32x16& o1,
                                          float (&den)[4]) {
  f32x16 acc;
#pragma unroll
  for (int r = 0; r < 16; r++) acc[r] = -12.0f;   // folds the 2^-12 P-scale
#pragma unroll
  for (int kt = 0; kt < 4; kt++)
    acc = __builtin_amdgcn_mfma_f32_32x32x16_f16(fk[kt], fq[kt], acc, 0, 0, 0);
  float p[16];
#pragma unroll
  for (int r = 0; r < 16; r++) {
    p[r] = fast_exp2(acc[r]);   // = exp(s)*2^-12 (K pre-scaled by log2e)
    den[r & 3] += p[r];
  }
  union PW { hf16x2 h; uint32_t w; };
  uint32_t u[8];
#pragma unroll
  for (int i = 0; i < 8; i++) {
    PW t; t.h = __builtin_amdgcn_cvt_pkrtz(p[2 * i], p[2 * i + 1]);
    u[i] = t.w;
  }
  asm("v_permlane32_swap_b32 %0, %1" : "+v"(u[0]), "+v"(u[2]));
  asm("v_permlane32_swap_b32 %0, %1" : "+v"(u[1]), "+v"(u[3]));
  asm("v_permlane32_swap_b32 %0, %1" : "+v"(u[4]), "+v"(u[6]));
  asm("v_permlane32_swap_b32 %0, %1" : "+v"(u[5]), "+v"(u[7]));
  union FR { uint32_t w[4]; f16x8 v; };
  FR fa0, fa1;
  fa0.w[0] = u[0]; fa0.w[1] = u[1]; fa0.w[2] = u[2]; fa0.w[3] = u[3];
  fa1.w[0] = u[4]; fa1.w[1] = u[5]; fa1.w[2] = u[6]; fa1.w[3] = u[7];
  o0 = __builtin_amdgcn_mfma_f32_32x32x16_f16(fa0.v, fv[0], o0, 0, 0, 0);
  o0 = __builtin_amdgcn_mfma_f32_32x32x16_f16(fa1.v, fv[1], o0, 0, 0, 0);
  o1 = __builtin_amdgcn_mfma_f32_32x32x16_f16(fa0.v, fv[2], o1, 0, 0, 0);
  o1 = __builtin_amdgcn_mfma_f32_32x32x16_f16(fa1.v, fv[3], o1, 0, 0, 0);
}

__global__ __launch_bounds__(256, 3) void attn_k(const f16* __restrict__ Qf,
                                                 const f16* __restrict__ Kf,
                                                 const f16* __restrict__ Vf,
                                                 f16* __restrict__ AO) {
  // [buf][tile: 0=fkA 1=fkB 2=fvA 3=fvB][chunk][512 halfs] = 32 KB
  __shared__ __align__(16) f16 kv[2][4][4][512];
  // XCD-chunked bijective swizzle (768 = 8 XCDs x 96), R19-verified.
  const int lid = blockIdx.y * 16 + blockIdx.x;
  const int wg = (lid & 7) * 96 + (lid >> 3);
  const int rb = wg & 15;
  const int bh = wg >> 4;
  const int b = bh / NHEAD, h = bh - b * NHEAD;
  const int w = threadIdx.x >> 6, l = threadIdx.x & 63;
  const int ln = l & 31, hi = l >> 5;
  const size_t base = (size_t)bh * SEQ * HDIM;
  const f16* Qfp = Qf + base;
  const f16* Kfp = Kf + base;
  const f16* Vfp = Vf + base;
  const int n0 = rb * 128 + w * 32;

  f16x8 fq[4];
#pragma unroll
  for (int kt = 0; kt < 4; kt++)
    fq[kt] = *reinterpret_cast<const f16x8*>(
        Kfp + ((((n0 >> 5) * 4 + kt) << 9) + (l << 3)));

  auto stage = [&](int bb, int it) {
    if (w < 2) {
      const int mc = 2 * it + w;
#pragma unroll
      for (int c = 0; c < 4; c++)
        gload_lds16(Qfp + (((mc * 4 + c) << 9) + (l << 3)), &kv[bb][w][c][0]);
    } else {
      const int m16 = 4 * it + (w - 2) * 2;
#pragma unroll
      for (int c = 0; c < 4; c++)
        gload_lds16(Vfp + ((((m16 + (c & 1)) * 2 + (c >> 1)) << 9) + (l << 3)),
                    &kv[bb][w][c][0]);
    }
  };
  auto ldfrag = [&](f16x8 (&fr)[4], int bb, int tile) {
#pragma unroll
    for (int c = 0; c < 4; c++)
      fr[c] = *reinterpret_cast<const f16x8*>(&kv[bb][tile][c][l << 3]);
  };

  f32x16 o0 = {}, o1 = {};
  float den[4] = {0.f, 0.f, 0.f, 0.f};
  stage(0, 0);
  asm volatile("s_waitcnt vmcnt(0)" ::: "memory");
  __builtin_amdgcn_s_barrier();
  int cur = 0;
  for (int it = 0; it < SEQ / 64; it++) {
    if (it + 1 < SEQ / 64) stage(cur ^ 1, it + 1);
    f16x8 fkA[4], fvA[4], fkB[4], fvB[4];
    ldfrag(fkA, cur, 0); ldfrag(fvA, cur, 2);
    attn_step(fkA, fvA, fq, o0, o1, den);
    ldfrag(fkB, cur, 1); ldfrag(fvB, cur, 3);
    attn_step(fkB, fvB, fq, o0, o1, den);
    asm volatile("s_waitcnt vmcnt(0)" ::: "memory");
    __builtin_amdgcn_s_barrier();
    cur ^= 1;
  }
  float d = (den[0] + den[1]) + (den[2] + den[3]);
  d += __shfl_xor(d, 32, 64);
  const float inv = SCALE_F / d;
#pragma unroll
  for (int r = 0; r < 16; r++) {
    const int nr = (r & 3) + 8 * (r >> 2) + 4 * hi;
    const float invr = __shfl(inv, nr, 64);
    const size_t row = ((size_t)(b * SEQ + n0 + nr)) * DMODEL + h * HDIM;
    AO[row + ln] = (f16)(o0[r] * invr);
    AO[row + 32 + ln] = (f16)(o1[r] * invr);
  }
}

extern "C" void kernel_launch(void* const* d_in, const int* in_sizes, int n_in,
                              void* d_out, int out_size, void* d_ws, size_t ws_size,
                              hipStream_t stream) {
  const float* x = (const float*)d_in[0];
  const float* Wqkv = (const float*)d_in[1];
  const float* bqkv = (const float*)d_in[2];
  const float* Wproj = (const float*)d_in[3];
  const float* bproj = (const float*)d_in[4];
  float* outp = (float*)d_out;

  // Workspace plan (52.5 MiB; R12-verified). AO aliases xh (dead after
  // gemm<0>); the old 64.5 MiB plan overflowed ws and caused R8-R11 flakes.
  f16* xh = (f16*)d_ws;                                  // [8192][768]
  f16* AO = xh;                                          // alias
  f16* wqkvt = xh + (size_t)NB_TOK * DMODEL;             // [2304][768]
  f16* wprojt = wqkvt + (size_t)QKV3 * DMODEL;           // [768][768]
  f16* Qf = wprojt + (size_t)DMODEL * DMODEL;            // frag layout
  f16* Kf = Qf + (size_t)NBATCH * NHEAD * SEQ * HDIM;
  f16* Vf = Kf + (size_t)NBATCH * NHEAD * SEQ * HDIM;

  cvt_f32_f16_k<<<(NB_TOK * DMODEL) / 1024, 256, 0, stream>>>(x, xh);
  transpose_cvt_k<<<(QKV3 * DMODEL) / 256, 256, 0, stream>>>(Wqkv, wqkvt, DMODEL, QKV3);
  transpose_cvt_k<<<(DMODEL * DMODEL) / 256, 256, 0, stream>>>(Wproj, wprojt, DMODEL, DMODEL);
  gemm128_k<0><<<dim3(QKV3 / 128, NB_TOK / 128), 256, 0, stream>>>(
      xh, wqkvt, bqkv, DMODEL, Qf, Kf, Vf, nullptr);
  attn_k<<<dim3(SEQ / 128, NBATCH * NHEAD), 256, 0, stream>>>(Qf, Kf, Vf, AO);
  gemm128_k<1><<<dim3(DMODEL / 128, NB_TOK / 128), 256, 0, stream>>>(
      AO, wprojt, bproj, DMODEL, nullptr, nullptr, nullptr, outp);
}

// Round 29
// 166.683 us; speedup vs baseline: 1.0188x; 1.0188x over previous
//
#include <hip/hip_runtime.h>
#include <stdint.h>

#define NB_TOK 8192   // B*N
#define DMODEL 768
#define NHEAD 12
#define HDIM 64
#define QKV3 2304
#define SEQ 2048
#define NBATCH 4
#define SCALE_F 0.125f
#define LOG2E 1.44269504f

typedef _Float16 f16;
typedef __attribute__((ext_vector_type(2))) __fp16 hf16x2;   // cvt_pkrtz return type
typedef __attribute__((ext_vector_type(4))) _Float16 f16x4;
typedef __attribute__((ext_vector_type(8))) _Float16 f16x8;
typedef __attribute__((ext_vector_type(4))) float f32x4;
typedef __attribute__((ext_vector_type(16))) float f32x16;

__device__ __forceinline__ void gload_lds16(const void* g, void* l) {
  __builtin_amdgcn_global_load_lds(
      (const __attribute__((address_space(1))) unsigned int*)g,
      (__attribute__((address_space(3))) unsigned int*)l, 16, 0, 0);
}

// bare v_exp_f32 via the intrinsic (R18-verified).
__device__ __forceinline__ float fast_exp2(float x) {
  return __builtin_amdgcn_exp2f(x);
}

// ---------------- converts ----------------
__global__ __launch_bounds__(256) void cvt_f32_f16_k(const float* __restrict__ in,
                                                     f16* __restrict__ out) {
  const int i = (blockIdx.x * 256 + threadIdx.x) * 4;
  const float4 v = *reinterpret_cast<const float4*>(in + i);
  f16x4 o;
  o[0] = (f16)v.x; o[1] = (f16)v.y; o[2] = (f16)v.z; o[3] = (f16)v.w;
  *reinterpret_cast<f16x4*>(out + i) = o;
}

// out[c][r] = in[r][c]  (output-linear; R28's input-linear flip was neutral-
// to-negative, reverted to the R27-verified form)
__global__ __launch_bounds__(256) void transpose_cvt_k(const float* __restrict__ in,
                                                       f16* __restrict__ out,
                                                       int R, int C) {
  const int idx = blockIdx.x * 256 + threadIdx.x;
  const int c = idx / R, r = idx - c * R;
  out[idx] = (f16)in[r * C + c];
}

// --- 128x128 MFMA GEMM, BK=32, 4 waves, 2-DEEP pipeline + XCD swizzle ------
// R22-VERIFIED (session best). MODE 0 epilogue writes Q/K/V in MFMA-FRAGMENT
// layout; K PRE-SCALED by LOG2E so attention uses exp2 directly.
template <int MODE>
__global__ __launch_bounds__(256) void gemm128_k(
    const f16* __restrict__ A, const f16* __restrict__ Bt,
    const float* __restrict__ bias, int K,
    f16* __restrict__ Qf, f16* __restrict__ Kf, f16* __restrict__ Vf,
    float* __restrict__ Of) {
  __shared__ __align__(16) f16 As[3][128 * 32];
  __shared__ __align__(16) f16 Bs[3][128 * 32];
  const int tid = threadIdx.x;
  const int w = tid >> 6, l = tid & 63;
  const int lr = l >> 2, lc = l & 3;
  const int nwg = gridDim.x * gridDim.y;
  const int lid = blockIdx.y * gridDim.x + blockIdx.x;
  const int wg = (lid & 7) * (nwg >> 3) + (lid >> 3);
  const int bm = (wg / gridDim.x) * 128, bn = (wg % gridDim.x) * 128;
  const f16* ga = A + (size_t)(bm + lr) * K + lc * 8;
  const f16* gb = Bt + (size_t)(bn + lr) * K + lc * 8;
  const int wr = (w >> 1) * 64, wc = (w & 1) * 64;
  const int fr = l & 15, fk = (l >> 4) * 8;

  auto stage = [&](int bb, int kt) {
    gload_lds16(ga + (size_t)(w * 16) * K + kt, &As[bb][(w * 16) * 32]);
    gload_lds16(ga + (size_t)((w + 4) * 16) * K + kt, &As[bb][((w + 4) * 16) * 32]);
    gload_lds16(gb + (size_t)(w * 16) * K + kt, &Bs[bb][(w * 16) * 32]);
    gload_lds16(gb + (size_t)((w + 4) * 16) * K + kt, &Bs[bb][((w + 4) * 16) * 32]);
  };

  f32x4 acc[4][4] = {};
  stage(0, 0);
  if (32 < K) stage(1, 32);
  int cur = 0;
  for (int kt = 0; kt < K; kt += 32) {
    if (kt + 64 < K) stage((cur + 2) % 3, kt + 64);
    if (kt + 64 < K)      asm volatile("s_waitcnt vmcnt(8)" ::: "memory");
    else if (kt + 32 < K) asm volatile("s_waitcnt vmcnt(4)" ::: "memory");
    else                  asm volatile("s_waitcnt vmcnt(0)" ::: "memory");
    __builtin_amdgcn_s_barrier();
    f16x8 af[4], bfrag[4];
#pragma unroll
    for (int mi = 0; mi < 4; mi++)
      af[mi] = *reinterpret_cast<const f16x8*>(&As[cur][(wr + mi * 16 + fr) * 32 + fk]);
#pragma unroll
    for (int ni = 0; ni < 4; ni++)
      bfrag[ni] = *reinterpret_cast<const f16x8*>(&Bs[cur][(wc + ni * 16 + fr) * 32 + fk]);
#pragma unroll
    for (int mi = 0; mi < 4; mi++)
#pragma unroll
      for (int ni = 0; ni < 4; ni++)
        acc[mi][ni] = __builtin_amdgcn_mfma_f32_16x16x32_f16(af[mi], bfrag[ni],
                                                             acc[mi][ni], 0, 0, 0);
    __builtin_amdgcn_s_barrier();
    cur = (cur + 1) % 3;
  }
  const int rgrp = (l >> 4) * 4;
#pragma unroll
  for (int ni = 0; ni < 4; ni++) {
    const int j = bn + wc + ni * 16 + fr;
    const float bb = bias[j];
    if (MODE == 0) {
      const int s = j / DMODEL;            // 0=Q 1=K 2=V, uniform per block
      const int rem = j - s * DMODEL;
      const int h = rem >> 6, hd = rem & 63;
      f16* dqk = (s == 0) ? Qf : Kf;
      const float scale = (s == 1) ? LOG2E : 1.0f;   // K pre-scaled for exp2
#pragma unroll
      for (int mi = 0; mi < 4; mi++)
#pragma unroll
        for (int r = 0; r < 4; r++) {
          const int m = bm + wr + mi * 16 + rgrp + r;   // global token
          const int bidx = m >> 11, n2 = m & 2047;      // batch, token-in-seq
          const f16 hv = (f16)((acc[mi][ni][r] + bb) * scale);
          const size_t bbase = (size_t)(bidx * NHEAD + h) * (SEQ * HDIM);
          if (s < 2) {
            const int mc = n2 >> 5, kt = hd >> 4;
            const int lane = (n2 & 31) + ((hd >> 3) & 1) * 32;
            dqk[bbase + (size_t)(((mc * 4 + kt) << 9) + (lane << 3) + (hd & 7))] = hv;
          } else {
            const int mc16 = n2 >> 4, g = hd >> 5;
            const int lane = (hd & 31) + ((n2 >> 3) & 1) * 32;
            Vf[bbase + (size_t)((((mc16 << 1) + g) << 9) + (lane << 3) + (n2 & 7))] = hv;
          }
        }
    } else {
#pragma unroll
      for (int mi = 0; mi < 4; mi++)
#pragma unroll
        for (int r = 0; r < 4; r++) {
          const int m = bm + wr + mi * 16 + rgrp + r;
          Of[(size_t)m * DMODEL + j] = acc[mi][ni][r] + bb;
        }
    }
  }
}

// ---------------- fused attention: LDS-staged shared K/V fragments ----------
// R22-VERIFIED. Three independent attn-structure modifications (R15 dacc,
// R24 tri-buffer, R26 dual-set) each failed correctness despite paper-proofs;
// this exact structure is the keeper.
__device__ __forceinline__ void attn_step(const f16x8 (&fk)[4], const f16x8 (&fv)[4],
                                          const f16x8 (&fq)[4], f32x16& o0, f32x16& o1,
                                          float (&den)[4]) {
  f32x16 acc;
#pragma unroll
  for (int r = 0; r < 16; r++) acc[r] = -12.0f;   // folds the 2^-12 P-scale
#pragma unroll
  for (int kt = 0; kt < 4; kt++)
    acc = __builtin_amdgcn_mfma_f32_32x32x16_f16(fk[kt], fq[kt], acc, 0, 0, 0);
  float p[16];
#pragma unroll
  for (int r = 0; r < 16; r++) {
    p[r] = fast_exp2(acc[r]);   // = exp(s)*2^-12 (K pre-scaled by log2e)
    den[r & 3] += p[r];
  }
  union PW { hf16x2 h; uint32_t w; };
  uint32_t u[8];
#pragma unroll
  for (int i = 0; i < 8; i++) {
    PW t; t.h = __builtin_amdgcn_cvt_pkrtz(p[2 * i], p[2 * i + 1]);
    u[i] = t.w;
  }
  asm("v_permlane32_swap_b32 %0, %1" : "+v"(u[0]), "+v"(u[2]));
  asm("v_permlane32_swap_b32 %0, %1" : "+v"(u[1]), "+v"(u[3]));
  asm("v_permlane32_swap_b32 %0, %1" : "+v"(u[4]), "+v"(u[6]));
  asm("v_permlane32_swap_b32 %0, %1" : "+v"(u[5]), "+v"(u[7]));
  union FR { uint32_t w[4]; f16x8 v; };
  FR fa0, fa1;
  fa0.w[0] = u[0]; fa0.w[1] = u[1]; fa0.w[2] = u[2]; fa0.w[3] = u[3];
  fa1.w[0] = u[4]; fa1.w[1] = u[5]; fa1.w[2] = u[6]; fa1.w[3] = u[7];
  o0 = __builtin_amdgcn_mfma_f32_32x32x16_f16(fa0.v, fv[0], o0, 0, 0, 0);
  o0 = __builtin_amdgcn_mfma_f32_32x32x16_f16(fa1.v, fv[1], o0, 0, 0, 0);
  o1 = __builtin_amdgcn_mfma_f32_32x32x16_f16(fa0.v, fv[2], o1, 0, 0, 0);
  o1 = __builtin_amdgcn_mfma_f32_32x32x16_f16(fa1.v, fv[3], o1, 0, 0, 0);
}

__global__ __launch_bounds__(256, 3) void attn_k(const f16* __restrict__ Qf,
                                                 const f16* __restrict__ Kf,
                                                 const f16* __restrict__ Vf,
                                                 f16* __restrict__ AO) {
  // [buf][tile: 0=fkA 1=fkB 2=fvA 3=fvB][chunk][512 halfs] = 32 KB
  __shared__ __align__(16) f16 kv[2][4][4][512];
  // XCD-chunked bijective swizzle (768 = 8 XCDs x 96), R19-verified.
  const int lid = blockIdx.y * 16 + blockIdx.x;
  const int wg = (lid & 7) * 96 + (lid >> 3);
  const int rb = wg & 15;
  const int bh = wg >> 4;
  const int b = bh / NHEAD, h = bh - b * NHEAD;
  const int w = threadIdx.x >> 6, l = threadIdx.x & 63;
  const int ln = l & 31, hi = l >> 5;
  const size_t base = (size_t)bh * SEQ * HDIM;
  const f16* Qfp = Qf + base;
  const f16* Kfp = Kf + base;
  const f16* Vfp = Vf + base;
  const int n0 = rb * 128 + w * 32;

  f16x8 fq[4];
#pragma unroll
  for (int kt = 0; kt < 4; kt++)
    fq[kt] = *reinterpret_cast<const f16x8*>(
        Kfp + ((((n0 >> 5) * 4 + kt) << 9) + (l << 3)));

  auto stage = [&](int bb, int it) {
    if (w < 2) {
      const int mc = 2 * it + w;
#pragma unroll
      for (int c = 0; c < 4; c++)
        gload_lds16(Qfp + (((mc * 4 + c) << 9) + (l << 3)), &kv[bb][w][c][0]);
    } else {
      const int m16 = 4 * it + (w - 2) * 2;
#pragma unroll
      for (int c = 0; c < 4; c++)
        gload_lds16(Vfp + ((((m16 + (c & 1)) * 2 + (c >> 1)) << 9) + (l << 3)),
                    &kv[bb][w][c][0]);
    }
  };
  auto ldfrag = [&](f16x8 (&fr)[4], int bb, int tile) {
#pragma unroll
    for (int c = 0; c < 4; c++)
      fr[c] = *reinterpret_cast<const f16x8*>(&kv[bb][tile][c][l << 3]);
  };

  f32x16 o0 = {}, o1 = {};
  float den[4] = {0.f, 0.f, 0.f, 0.f};
  stage(0, 0);
  asm volatile("s_waitcnt vmcnt(0)" ::: "memory");
  __builtin_amdgcn_s_barrier();
  int cur = 0;
  for (int it = 0; it < SEQ / 64; it++) {
    if (it + 1 < SEQ / 64) stage(cur ^ 1, it + 1);
    f16x8 fkA[4], fvA[4], fkB[4], fvB[4];
    ldfrag(fkA, cur, 0); ldfrag(fvA, cur, 2);
    attn_step(fkA, fvA, fq, o0, o1, den);
    ldfrag(fkB, cur, 1); ldfrag(fvB, cur, 3);
    attn_step(fkB, fvB, fq, o0, o1, den);
    asm volatile("s_waitcnt vmcnt(0)" ::: "memory");
    __builtin_amdgcn_s_barrier();
    cur ^= 1;
  }
  float d = (den[0] + den[1]) + (den[2] + den[3]);
  d += __shfl_xor(d, 32, 64);
  const float inv = SCALE_F / d;
#pragma unroll
  for (int r = 0; r < 16; r++) {
    const int nr = (r & 3) + 8 * (r >> 2) + 4 * hi;
    const float invr = __shfl(inv, nr, 64);
    const size_t row = ((size_t)(b * SEQ + n0 + nr)) * DMODEL + h * HDIM;
    AO[row + ln] = (f16)(o0[r] * invr);
    AO[row + 32 + ln] = (f16)(o1[r] * invr);
  }
}

extern "C" void kernel_launch(void* const* d_in, const int* in_sizes, int n_in,
                              void* d_out, int out_size, void* d_ws, size_t ws_size,
                              hipStream_t stream) {
  const float* x = (const float*)d_in[0];
  const float* Wqkv = (const float*)d_in[1];
  const float* bqkv = (const float*)d_in[2];
  const float* Wproj = (const float*)d_in[3];
  const float* bproj = (const float*)d_in[4];
  float* outp = (float*)d_out;

  // Workspace plan (52.5 MiB; R12-verified). AO aliases xh (dead after
  // gemm<0>); the old 64.5 MiB plan overflowed ws and caused R8-R11 flakes.
  f16* xh = (f16*)d_ws;                                  // [8192][768]
  f16* AO = xh;                                          // alias
  f16* wqkvt = xh + (size_t)NB_TOK * DMODEL;             // [2304][768]
  f16* wprojt = wqkvt + (size_t)QKV3 * DMODEL;           // [768][768]
  f16* Qf = wprojt + (size_t)DMODEL * DMODEL;            // frag layout
  f16* Kf = Qf + (size_t)NBATCH * NHEAD * SEQ * HDIM;
  f16* Vf = Kf + (size_t)NBATCH * NHEAD * SEQ * HDIM;

  cvt_f32_f16_k<<<(NB_TOK * DMODEL) / 1024, 256, 0, stream>>>(x, xh);
  transpose_cvt_k<<<(QKV3 * DMODEL) / 256, 256, 0, stream>>>(Wqkv, wqkvt, DMODEL, QKV3);
  transpose_cvt_k<<<(DMODEL * DMODEL) / 256, 256, 0, stream>>>(Wproj, wprojt, DMODEL, DMODEL);
  gemm128_k<0><<<dim3(QKV3 / 128, NB_TOK / 128), 256, 0, stream>>>(
      xh, wqkvt, bqkv, DMODEL, Qf, Kf, Vf, nullptr);
  attn_k<<<dim3(SEQ / 128, NBATCH * NHEAD), 256, 0, stream>>>(Qf, Kf, Vf, AO);
  gemm128_k<1><<<dim3(DMODEL / 128, NB_TOK / 128), 256, 0, stream>>>(
      AO, wprojt, bproj, DMODEL, nullptr, nullptr, nullptr, outp);
}

// Round 30
// 161.957 us; speedup vs baseline: 1.0485x; 1.0292x over previous
//
#include <hip/hip_runtime.h>
#include <stdint.h>

#define NB_TOK 8192   // B*N
#define DMODEL 768
#define NHEAD 12
#define HDIM 64
#define QKV3 2304
#define SEQ 2048
#define NBATCH 4
#define SCALE_F 0.125f
#define LOG2E 1.44269504f

typedef _Float16 f16;
typedef __attribute__((ext_vector_type(2))) __fp16 hf16x2;   // cvt_pkrtz return type
typedef __attribute__((ext_vector_type(4))) _Float16 f16x4;
typedef __attribute__((ext_vector_type(8))) _Float16 f16x8;
typedef __attribute__((ext_vector_type(4))) float f32x4;
typedef __attribute__((ext_vector_type(16))) float f32x16;

__device__ __forceinline__ void gload_lds16(const void* g, void* l) {
  __builtin_amdgcn_global_load_lds(
      (const __attribute__((address_space(1))) unsigned int*)g,
      (__attribute__((address_space(3))) unsigned int*)l, 16, 0, 0);
}

// bare v_exp_f32 via the intrinsic (R18-verified).
__device__ __forceinline__ float fast_exp2(float x) {
  return __builtin_amdgcn_exp2f(x);
}

// -------- fused prologue: x f32->f16 + both weight transposes, ONE launch ---
// Region bodies are verbatim copies of the R29-verified cvt/transpose kernels;
// the region switch is block-uniform. Saves two launch gaps.
#define CVT_BLKS 6144    // 8192*768/1024
#define WQKV_BLKS 6912   // 2304*768/256
#define WPROJ_BLKS 2304  // 768*768/256
__global__ __launch_bounds__(256) void prep_k(
    const float* __restrict__ x, f16* __restrict__ xh,
    const float* __restrict__ Wqkv, f16* __restrict__ wqkvt,
    const float* __restrict__ Wproj, f16* __restrict__ wprojt) {
  const int bid = blockIdx.x;
  if (bid < CVT_BLKS) {
    const int i = (bid * 256 + threadIdx.x) * 4;
    const float4 v = *reinterpret_cast<const float4*>(x + i);
    f16x4 o;
    o[0] = (f16)v.x; o[1] = (f16)v.y; o[2] = (f16)v.z; o[3] = (f16)v.w;
    *reinterpret_cast<f16x4*>(xh + i) = o;
  } else if (bid < CVT_BLKS + WQKV_BLKS) {
    // wqkvt[c][r] = Wqkv[r][c], output-linear (R=DMODEL, C=QKV3)
    const int idx = (bid - CVT_BLKS) * 256 + threadIdx.x;
    const int c = idx / DMODEL, r = idx - c * DMODEL;
    wqkvt[idx] = (f16)Wqkv[r * QKV3 + c];
  } else {
    // wprojt[c][r] = Wproj[r][c], output-linear (R=C=DMODEL)
    const int idx = (bid - CVT_BLKS - WQKV_BLKS) * 256 + threadIdx.x;
    const int c = idx / DMODEL, r = idx - c * DMODEL;
    wprojt[idx] = (f16)Wproj[r * DMODEL + c];
  }
}

// --- 128x128 MFMA GEMM, BK=32, 4 waves, 2-DEEP pipeline + XCD swizzle ------
// R22-VERIFIED (session best). MODE 0 epilogue writes Q/K/V in MFMA-FRAGMENT
// layout; K PRE-SCALED by LOG2E so attention uses exp2 directly.
template <int MODE>
__global__ __launch_bounds__(256) void gemm128_k(
    const f16* __restrict__ A, const f16* __restrict__ Bt,
    const float* __restrict__ bias, int K,
    f16* __restrict__ Qf, f16* __restrict__ Kf, f16* __restrict__ Vf,
    float* __restrict__ Of) {
  __shared__ __align__(16) f16 As[3][128 * 32];
  __shared__ __align__(16) f16 Bs[3][128 * 32];
  const int tid = threadIdx.x;
  const int w = tid >> 6, l = tid & 63;
  const int lr = l >> 2, lc = l & 3;
  const int nwg = gridDim.x * gridDim.y;
  const int lid = blockIdx.y * gridDim.x + blockIdx.x;
  const int wg = (lid & 7) * (nwg >> 3) + (lid >> 3);
  const int bm = (wg / gridDim.x) * 128, bn = (wg % gridDim.x) * 128;
  const f16* ga = A + (size_t)(bm + lr) * K + lc * 8;
  const f16* gb = Bt + (size_t)(bn + lr) * K + lc * 8;
  const int wr = (w >> 1) * 64, wc = (w & 1) * 64;
  const int fr = l & 15, fk = (l >> 4) * 8;

  auto stage = [&](int bb, int kt) {
    gload_lds16(ga + (size_t)(w * 16) * K + kt, &As[bb][(w * 16) * 32]);
    gload_lds16(ga + (size_t)((w + 4) * 16) * K + kt, &As[bb][((w + 4) * 16) * 32]);
    gload_lds16(gb + (size_t)(w * 16) * K + kt, &Bs[bb][(w * 16) * 32]);
    gload_lds16(gb + (size_t)((w + 4) * 16) * K + kt, &Bs[bb][((w + 4) * 16) * 32]);
  };

  f32x4 acc[4][4] = {};
  stage(0, 0);
  if (32 < K) stage(1, 32);
  int cur = 0;
  for (int kt = 0; kt < K; kt += 32) {
    if (kt + 64 < K) stage((cur + 2) % 3, kt + 64);
    if (kt + 64 < K)      asm volatile("s_waitcnt vmcnt(8)" ::: "memory");
    else if (kt + 32 < K) asm volatile("s_waitcnt vmcnt(4)" ::: "memory");
    else                  asm volatile("s_waitcnt vmcnt(0)" ::: "memory");
    __builtin_amdgcn_s_barrier();
    f16x8 af[4], bfrag[4];
#pragma unroll
    for (int mi = 0; mi < 4; mi++)
      af[mi] = *reinterpret_cast<const f16x8*>(&As[cur][(wr + mi * 16 + fr) * 32 + fk]);
#pragma unroll
    for (int ni = 0; ni < 4; ni++)
      bfrag[ni] = *reinterpret_cast<const f16x8*>(&Bs[cur][(wc + ni * 16 + fr) * 32 + fk]);
#pragma unroll
    for (int mi = 0; mi < 4; mi++)
#pragma unroll
      for (int ni = 0; ni < 4; ni++)
        acc[mi][ni] = __builtin_amdgcn_mfma_f32_16x16x32_f16(af[mi], bfrag[ni],
                                                             acc[mi][ni], 0, 0, 0);
    __builtin_amdgcn_s_barrier();
    cur = (cur + 1) % 3;
  }
  const int rgrp = (l >> 4) * 4;
#pragma unroll
  for (int ni = 0; ni < 4; ni++) {
    const int j = bn + wc + ni * 16 + fr;
    const float bb = bias[j];
    if (MODE == 0) {
      const int s = j / DMODEL;            // 0=Q 1=K 2=V, uniform per block
      const int rem = j - s * DMODEL;
      const int h = rem >> 6, hd = rem & 63;
      f16* dqk = (s == 0) ? Qf : Kf;
      const float scale = (s == 1) ? LOG2E : 1.0f;   // K pre-scaled for exp2
#pragma unroll
      for (int mi = 0; mi < 4; mi++)
#pragma unroll
        for (int r = 0; r < 4; r++) {
          const int m = bm + wr + mi * 16 + rgrp + r;   // global token
          const int bidx = m >> 11, n2 = m & 2047;      // batch, token-in-seq
          const f16 hv = (f16)((acc[mi][ni][r] + bb) * scale);
          const size_t bbase = (size_t)(bidx * NHEAD + h) * (SEQ * HDIM);
          if (s < 2) {
            const int mc = n2 >> 5, kt = hd >> 4;
            const int lane = (n2 & 31) + ((hd >> 3) & 1) * 32;
            dqk[bbase + (size_t)(((mc * 4 + kt) << 9) + (lane << 3) + (hd & 7))] = hv;
          } else {
            const int mc16 = n2 >> 4, g = hd >> 5;
            const int lane = (hd & 31) + ((n2 >> 3) & 1) * 32;
            Vf[bbase + (size_t)((((mc16 << 1) + g) << 9) + (lane << 3) + (n2 & 7))] = hv;
          }
        }
    } else {
#pragma unroll
      for (int mi = 0; mi < 4; mi++)
#pragma unroll
        for (int r = 0; r < 4; r++) {
          const int m = bm + wr + mi * 16 + rgrp + r;
          Of[(size_t)m * DMODEL + j] = acc[mi][ni][r] + bb;
        }
    }
  }
}

// ---------------- fused attention: LDS-staged shared K/V fragments ----------
// R22-VERIFIED. Three independent attn-structure modifications (R15 dacc,
// R24 tri-buffer, R26 dual-set) each failed correctness despite paper-proofs;
// this exact structure is the keeper.
__device__ __forceinline__ void attn_step(const f16x8 (&fk)[4], const f16x8 (&fv)[4],
                                          const f16x8 (&fq)[4], f32x16& o0, f32x16& o1,
                                          float (&den)[4]) {
  f32x16 acc;
#pragma unroll
  for (int r = 0; r < 16; r++) acc[r] = -12.0f;   // folds the 2^-12 P-scale
#pragma unroll
  for (int kt = 0; kt < 4; kt++)
    acc = __builtin_amdgcn_mfma_f32_32x32x16_f16(fk[kt], fq[kt], acc, 0, 0, 0);
  float p[16];
#pragma unroll
  for (int r = 0; r < 16; r++) {
    p[r] = fast_exp2(acc[r]);   // = exp(s)*2^-12 (K pre-scaled by log2e)
    den[r & 3] += p[r];
  }
  union PW { hf16x2 h; uint32_t w; };
  uint32_t u[8];
#pragma unroll
  for (int i = 0; i < 8; i++) {
    PW t; t.h = __builtin_amdgcn_cvt_pkrtz(p[2 * i], p[2 * i + 1]);
    u[i] = t.w;
  }
  asm("v_permlane32_swap_b32 %0, %1" : "+v"(u[0]), "+v"(u[2]));
  asm("v_permlane32_swap_b32 %0, %1" : "+v"(u[1]), "+v"(u[3]));
  asm("v_permlane32_swap_b32 %0, %1" : "+v"(u[4]), "+v"(u[6]));
  asm("v_permlane32_swap_b32 %0, %1" : "+v"(u[5]), "+v"(u[7]));
  union FR { uint32_t w[4]; f16x8 v; };
  FR fa0, fa1;
  fa0.w[0] = u[0]; fa0.w[1] = u[1]; fa0.w[2] = u[2]; fa0.w[3] = u[3];
  fa1.w[0] = u[4]; fa1.w[1] = u[5]; fa1.w[2] = u[6]; fa1.w[3] = u[7];
  o0 = __builtin_amdgcn_mfma_f32_32x32x16_f16(fa0.v, fv[0], o0, 0, 0, 0);
  o0 = __builtin_amdgcn_mfma_f32_32x32x16_f16(fa1.v, fv[1], o0, 0, 0, 0);
  o1 = __builtin_amdgcn_mfma_f32_32x32x16_f16(fa0.v, fv[2], o1, 0, 0, 0);
  o1 = __builtin_amdgcn_mfma_f32_32x32x16_f16(fa1.v, fv[3], o1, 0, 0, 0);
}

__global__ __launch_bounds__(256, 3) void attn_k(const f16* __restrict__ Qf,
                                                 const f16* __restrict__ Kf,
                                                 const f16* __restrict__ Vf,
                                                 f16* __restrict__ AO) {
  // [buf][tile: 0=fkA 1=fkB 2=fvA 3=fvB][chunk][512 halfs] = 32 KB
  __shared__ __align__(16) f16 kv[2][4][4][512];
  // XCD-chunked bijective swizzle (768 = 8 XCDs x 96), R19-verified.
  const int lid = blockIdx.y * 16 + blockIdx.x;
  const int wg = (lid & 7) * 96 + (lid >> 3);
  const int rb = wg & 15;
  const int bh = wg >> 4;
  const int b = bh / NHEAD, h = bh - b * NHEAD;
  const int w = threadIdx.x >> 6, l = threadIdx.x & 63;
  const int ln = l & 31, hi = l >> 5;
  const size_t base = (size_t)bh * SEQ * HDIM;
  const f16* Qfp = Qf + base;
  const f16* Kfp = Kf + base;
  const f16* Vfp = Vf + base;
  const int n0 = rb * 128 + w * 32;

  f16x8 fq[4];
#pragma unroll
  for (int kt = 0; kt < 4; kt++)
    fq[kt] = *reinterpret_cast<const f16x8*>(
        Kfp + ((((n0 >> 5) * 4 + kt) << 9) + (l << 3)));

  auto stage = [&](int bb, int it) {
    if (w < 2) {
      const int mc = 2 * it + w;
#pragma unroll
      for (int c = 0; c < 4; c++)
        gload_lds16(Qfp + (((mc * 4 + c) << 9) + (l << 3)), &kv[bb][w][c][0]);
    } else {
      const int m16 = 4 * it + (w - 2) * 2;
#pragma unroll
      for (int c = 0; c < 4; c++)
        gload_lds16(Vfp + ((((m16 + (c & 1)) * 2 + (c >> 1)) << 9) + (l << 3)),
                    &kv[bb][w][c][0]);
    }
  };
  auto ldfrag = [&](f16x8 (&fr)[4], int bb, int tile) {
#pragma unroll
    for (int c = 0; c < 4; c++)
      fr[c] = *reinterpret_cast<const f16x8*>(&kv[bb][tile][c][l << 3]);
  };

  f32x16 o0 = {}, o1 = {};
  float den[4] = {0.f, 0.f, 0.f, 0.f};
  stage(0, 0);
  asm volatile("s_waitcnt vmcnt(0)" ::: "memory");
  __builtin_amdgcn_s_barrier();
  int cur = 0;
  for (int it = 0; it < SEQ / 64; it++) {
    if (it + 1 < SEQ / 64) stage(cur ^ 1, it + 1);
    f16x8 fkA[4], fvA[4], fkB[4], fvB[4];
    ldfrag(fkA, cur, 0); ldfrag(fvA, cur, 2);
    attn_step(fkA, fvA, fq, o0, o1, den);
    ldfrag(fkB, cur, 1); ldfrag(fvB, cur, 3);
    attn_step(fkB, fvB, fq, o0, o1, den);
    asm volatile("s_waitcnt vmcnt(0)" ::: "memory");
    __builtin_amdgcn_s_barrier();
    cur ^= 1;
  }
  float d = (den[0] + den[1]) + (den[2] + den[3]);
  d += __shfl_xor(d, 32, 64);
  const float inv = SCALE_F / d;
#pragma unroll
  for (int r = 0; r < 16; r++) {
    const int nr = (r & 3) + 8 * (r >> 2) + 4 * hi;
    const float invr = __shfl(inv, nr, 64);
    const size_t row = ((size_t)(b * SEQ + n0 + nr)) * DMODEL + h * HDIM;
    AO[row + ln] = (f16)(o0[r] * invr);
    AO[row + 32 + ln] = (f16)(o1[r] * invr);
  }
}

extern "C" void kernel_launch(void* const* d_in, const int* in_sizes, int n_in,
                              void* d_out, int out_size, void* d_ws, size_t ws_size,
                              hipStream_t stream) {
  const float* x = (const float*)d_in[0];
  const float* Wqkv = (const float*)d_in[1];
  const float* bqkv = (const float*)d_in[2];
  const float* Wproj = (const float*)d_in[3];
  const float* bproj = (const float*)d_in[4];
  float* outp = (float*)d_out;

  // Workspace plan (52.5 MiB; R12-verified). AO aliases xh (dead after
  // gemm<0>); the old 64.5 MiB plan overflowed ws and caused R8-R11 flakes.
  f16* xh = (f16*)d_ws;                                  // [8192][768]
  f16* AO = xh;                                          // alias
  f16* wqkvt = xh + (size_t)NB_TOK * DMODEL;             // [2304][768]
  f16* wprojt = wqkvt + (size_t)QKV3 * DMODEL;           // [768][768]
  f16* Qf = wprojt + (size_t)DMODEL * DMODEL;            // frag layout
  f16* Kf = Qf + (size_t)NBATCH * NHEAD * SEQ * HDIM;
  f16* Vf = Kf + (size_t)NBATCH * NHEAD * SEQ * HDIM;

  prep_k<<<CVT_BLKS + WQKV_BLKS + WPROJ_BLKS, 256, 0, stream>>>(
      x, xh, Wqkv, wqkvt, Wproj, wprojt);
  gemm128_k<0><<<dim3(QKV3 / 128, NB_TOK / 128), 256, 0, stream>>>(
      xh, wqkvt, bqkv, DMODEL, Qf, Kf, Vf, nullptr);
  attn_k<<<dim3(SEQ / 128, NBATCH * NHEAD), 256, 0, stream>>>(Qf, Kf, Vf, AO);
  gemm128_k<1><<<dim3(DMODEL / 128, NB_TOK / 128), 256, 0, stream>>>(
      AO, wprojt, bproj, DMODEL, nullptr, nullptr, nullptr, outp);
}

// Round 31
// 153.349 us; speedup vs baseline: 1.1073x; 1.0561x over previous
//
#include <hip/hip_runtime.h>
#include <stdint.h>

#define NB_TOK 8192   // B*N
#define DMODEL 768
#define NHEAD 12
#define HDIM 64
#define QKV3 2304
#define SEQ 2048
#define NBATCH 4
#define SCALE_F 0.125f
#define LOG2E 1.44269504f

typedef _Float16 f16;
typedef __attribute__((ext_vector_type(2))) __fp16 hf16x2;   // cvt_pkrtz return type
typedef __attribute__((ext_vector_type(4))) _Float16 f16x4;
typedef __attribute__((ext_vector_type(8))) _Float16 f16x8;
typedef __attribute__((ext_vector_type(4))) float f32x4;
typedef __attribute__((ext_vector_type(16))) float f32x16;

__device__ __forceinline__ void gload_lds16(const void* g, void* l) {
  __builtin_amdgcn_global_load_lds(
      (const __attribute__((address_space(1))) unsigned int*)g,
      (__attribute__((address_space(3))) unsigned int*)l, 16, 0, 0);
}

// bare v_exp_f32 via the intrinsic (R18-verified).
__device__ __forceinline__ float fast_exp2(float x) {
  return __builtin_amdgcn_exp2f(x);
}

// -------- fused prologue: x cvt + LDS-TILED weight transposes, ONE launch ---
// R30-verified fusion; transposes upgraded to 32x32 LDS tiles (coalesced
// reads AND writes; tile[32][33] padding kills bank conflicts). Region
// switch is block-uniform, so the __syncthreads inside a region is legal.
#define CVT_BLKS 6144     // 8192*768/1024
#define WQKV_TILES 1728   // (768/32)*(2304/32)
#define WPROJ_TILES 576   // (768/32)*(768/32)
__global__ __launch_bounds__(256) void prep_k(
    const float* __restrict__ x, f16* __restrict__ xh,
    const float* __restrict__ Wqkv, f16* __restrict__ wqkvt,
    const float* __restrict__ Wproj, f16* __restrict__ wprojt) {
  __shared__ float tile[32][33];
  const int bid = blockIdx.x;
  if (bid < CVT_BLKS) {
    const int i = (bid * 256 + threadIdx.x) * 4;
    const float4 v = *reinterpret_cast<const float4*>(x + i);
    f16x4 o;
    o[0] = (f16)v.x; o[1] = (f16)v.y; o[2] = (f16)v.z; o[3] = (f16)v.w;
    *reinterpret_cast<f16x4*>(xh + i) = o;
  } else if (bid < CVT_BLKS + WQKV_TILES) {
    // wqkvt[c][r] = Wqkv[r][c]; R=768 rows, C=2304 cols; 32x32 tile per block
    const int t = bid - CVT_BLKS;
    const int ntc = QKV3 / 32;                       // 72 tiles along C
    const int tr = t / ntc, tc = t - tr * ntc;
    const int tx = threadIdx.x & 31, ty = threadIdx.x >> 5;   // 32x8
#pragma unroll
    for (int i = 0; i < 4; i++)
      tile[ty + i * 8][tx] =
          Wqkv[(size_t)(tr * 32 + ty + i * 8) * QKV3 + tc * 32 + tx];
    __syncthreads();
#pragma unroll
    for (int i = 0; i < 4; i++)
      wqkvt[(size_t)(tc * 32 + ty + i * 8) * DMODEL + tr * 32 + tx] =
          (f16)tile[tx][ty + i * 8];
  } else {
    // wprojt[c][r] = Wproj[r][c]; R=C=768
    const int t = bid - CVT_BLKS - WQKV_TILES;
    const int ntc = DMODEL / 32;                     // 24 tiles along C
    const int tr = t / ntc, tc = t - tr * ntc;
    const int tx = threadIdx.x & 31, ty = threadIdx.x >> 5;
#pragma unroll
    for (int i = 0; i < 4; i++)
      tile[ty + i * 8][tx] =
          Wproj[(size_t)(tr * 32 + ty + i * 8) * DMODEL + tc * 32 + tx];
    __syncthreads();
#pragma unroll
    for (int i = 0; i < 4; i++)
      wprojt[(size_t)(tc * 32 + ty + i * 8) * DMODEL + tr * 32 + tx] =
          (f16)tile[tx][ty + i * 8];
  }
}

// --- 128x128 MFMA GEMM, BK=32, 4 waves, 2-DEEP pipeline + XCD swizzle ------
// R22-VERIFIED (session best). MODE 0 epilogue writes Q/K/V in MFMA-FRAGMENT
// layout; K PRE-SCALED by LOG2E so attention uses exp2 directly.
template <int MODE>
__global__ __launch_bounds__(256) void gemm128_k(
    const f16* __restrict__ A, const f16* __restrict__ Bt,
    const float* __restrict__ bias, int K,
    f16* __restrict__ Qf, f16* __restrict__ Kf, f16* __restrict__ Vf,
    float* __restrict__ Of) {
  __shared__ __align__(16) f16 As[3][128 * 32];
  __shared__ __align__(16) f16 Bs[3][128 * 32];
  const int tid = threadIdx.x;
  const int w = tid >> 6, l = tid & 63;
  const int lr = l >> 2, lc = l & 3;
  const int nwg = gridDim.x * gridDim.y;
  const int lid = blockIdx.y * gridDim.x + blockIdx.x;
  const int wg = (lid & 7) * (nwg >> 3) + (lid >> 3);
  const int bm = (wg / gridDim.x) * 128, bn = (wg % gridDim.x) * 128;
  const f16* ga = A + (size_t)(bm + lr) * K + lc * 8;
  const f16* gb = Bt + (size_t)(bn + lr) * K + lc * 8;
  const int wr = (w >> 1) * 64, wc = (w & 1) * 64;
  const int fr = l & 15, fk = (l >> 4) * 8;

  auto stage = [&](int bb, int kt) {
    gload_lds16(ga + (size_t)(w * 16) * K + kt, &As[bb][(w * 16) * 32]);
    gload_lds16(ga + (size_t)((w + 4) * 16) * K + kt, &As[bb][((w + 4) * 16) * 32]);
    gload_lds16(gb + (size_t)(w * 16) * K + kt, &Bs[bb][(w * 16) * 32]);
    gload_lds16(gb + (size_t)((w + 4) * 16) * K + kt, &Bs[bb][((w + 4) * 16) * 32]);
  };

  f32x4 acc[4][4] = {};
  stage(0, 0);
  if (32 < K) stage(1, 32);
  int cur = 0;
  for (int kt = 0; kt < K; kt += 32) {
    if (kt + 64 < K) stage((cur + 2) % 3, kt + 64);
    if (kt + 64 < K)      asm volatile("s_waitcnt vmcnt(8)" ::: "memory");
    else if (kt + 32 < K) asm volatile("s_waitcnt vmcnt(4)" ::: "memory");
    else                  asm volatile("s_waitcnt vmcnt(0)" ::: "memory");
    __builtin_amdgcn_s_barrier();
    f16x8 af[4], bfrag[4];
#pragma unroll
    for (int mi = 0; mi < 4; mi++)
      af[mi] = *reinterpret_cast<const f16x8*>(&As[cur][(wr + mi * 16 + fr) * 32 + fk]);
#pragma unroll
    for (int ni = 0; ni < 4; ni++)
      bfrag[ni] = *reinterpret_cast<const f16x8*>(&Bs[cur][(wc + ni * 16 + fr) * 32 + fk]);
#pragma unroll
    for (int mi = 0; mi < 4; mi++)
#pragma unroll
      for (int ni = 0; ni < 4; ni++)
        acc[mi][ni] = __builtin_amdgcn_mfma_f32_16x16x32_f16(af[mi], bfrag[ni],
                                                             acc[mi][ni], 0, 0, 0);
    __builtin_amdgcn_s_barrier();
    cur = (cur + 1) % 3;
  }
  const int rgrp = (l >> 4) * 4;
#pragma unroll
  for (int ni = 0; ni < 4; ni++) {
    const int j = bn + wc + ni * 16 + fr;
    const float bb = bias[j];
    if (MODE == 0) {
      const int s = j / DMODEL;            // 0=Q 1=K 2=V, uniform per block
      const int rem = j - s * DMODEL;
      const int h = rem >> 6, hd = rem & 63;
      f16* dqk = (s == 0) ? Qf : Kf;
      const float scale = (s == 1) ? LOG2E : 1.0f;   // K pre-scaled for exp2
#pragma unroll
      for (int mi = 0; mi < 4; mi++)
#pragma unroll
        for (int r = 0; r < 4; r++) {
          const int m = bm + wr + mi * 16 + rgrp + r;   // global token
          const int bidx = m >> 11, n2 = m & 2047;      // batch, token-in-seq
          const f16 hv = (f16)((acc[mi][ni][r] + bb) * scale);
          const size_t bbase = (size_t)(bidx * NHEAD + h) * (SEQ * HDIM);
          if (s < 2) {
            const int mc = n2 >> 5, kt = hd >> 4;
            const int lane = (n2 & 31) + ((hd >> 3) & 1) * 32;
            dqk[bbase + (size_t)(((mc * 4 + kt) << 9) + (lane << 3) + (hd & 7))] = hv;
          } else {
            const int mc16 = n2 >> 4, g = hd >> 5;
            const int lane = (hd & 31) + ((n2 >> 3) & 1) * 32;
            Vf[bbase + (size_t)((((mc16 << 1) + g) << 9) + (lane << 3) + (n2 & 7))] = hv;
          }
        }
    } else {
#pragma unroll
      for (int mi = 0; mi < 4; mi++)
#pragma unroll
        for (int r = 0; r < 4; r++) {
          const int m = bm + wr + mi * 16 + rgrp + r;
          Of[(size_t)m * DMODEL + j] = acc[mi][ni][r] + bb;
        }
    }
  }
}

// ---------------- fused attention: LDS-staged shared K/V fragments ----------
// R22-VERIFIED. Three independent attn-structure modifications (R15 dacc,
// R24 tri-buffer, R26 dual-set) each failed correctness despite paper-proofs;
// this exact structure is the keeper.
__device__ __forceinline__ void attn_step(const f16x8 (&fk)[4], const f16x8 (&fv)[4],
                                          const f16x8 (&fq)[4], f32x16& o0, f32x16& o1,
                                          float (&den)[4]) {
  f32x16 acc;
#pragma unroll
  for (int r = 0; r < 16; r++) acc[r] = -12.0f;   // folds the 2^-12 P-scale
#pragma unroll
  for (int kt = 0; kt < 4; kt++)
    acc = __builtin_amdgcn_mfma_f32_32x32x16_f16(fk[kt], fq[kt], acc, 0, 0, 0);
  float p[16];
#pragma unroll
  for (int r = 0; r < 16; r++) {
    p[r] = fast_exp2(acc[r]);   // = exp(s)*2^-12 (K pre-scaled by log2e)
    den[r & 3] += p[r];
  }
  union PW { hf16x2 h; uint32_t w; };
  uint32_t u[8];
#pragma unroll
  for (int i = 0; i < 8; i++) {
    PW t; t.h = __builtin_amdgcn_cvt_pkrtz(p[2 * i], p[2 * i + 1]);
    u[i] = t.w;
  }
  asm("v_permlane32_swap_b32 %0, %1" : "+v"(u[0]), "+v"(u[2]));
  asm("v_permlane32_swap_b32 %0, %1" : "+v"(u[1]), "+v"(u[3]));
  asm("v_permlane32_swap_b32 %0, %1" : "+v"(u[4]), "+v"(u[6]));
  asm("v_permlane32_swap_b32 %0, %1" : "+v"(u[5]), "+v"(u[7]));
  union FR { uint32_t w[4]; f16x8 v; };
  FR fa0, fa1;
  fa0.w[0] = u[0]; fa0.w[1] = u[1]; fa0.w[2] = u[2]; fa0.w[3] = u[3];
  fa1.w[0] = u[4]; fa1.w[1] = u[5]; fa1.w[2] = u[6]; fa1.w[3] = u[7];
  o0 = __builtin_amdgcn_mfma_f32_32x32x16_f16(fa0.v, fv[0], o0, 0, 0, 0);
  o0 = __builtin_amdgcn_mfma_f32_32x32x16_f16(fa1.v, fv[1], o0, 0, 0, 0);
  o1 = __builtin_amdgcn_mfma_f32_32x32x16_f16(fa0.v, fv[2], o1, 0, 0, 0);
  o1 = __builtin_amdgcn_mfma_f32_32x32x16_f16(fa1.v, fv[3], o1, 0, 0, 0);
}

__global__ __launch_bounds__(256, 3) void attn_k(const f16* __restrict__ Qf,
                                                 const f16* __restrict__ Kf,
                                                 const f16* __restrict__ Vf,
                                                 f16* __restrict__ AO) {
  // [buf][tile: 0=fkA 1=fkB 2=fvA 3=fvB][chunk][512 halfs] = 32 KB
  __shared__ __align__(16) f16 kv[2][4][4][512];
  // XCD-chunked bijective swizzle (768 = 8 XCDs x 96), R19-verified.
  const int lid = blockIdx.y * 16 + blockIdx.x;
  const int wg = (lid & 7) * 96 + (lid >> 3);
  const int rb = wg & 15;
  const int bh = wg >> 4;
  const int b = bh / NHEAD, h = bh - b * NHEAD;
  const int w = threadIdx.x >> 6, l = threadIdx.x & 63;
  const int ln = l & 31, hi = l >> 5;
  const size_t base = (size_t)bh * SEQ * HDIM;
  const f16* Qfp = Qf + base;
  const f16* Kfp = Kf + base;
  const f16* Vfp = Vf + base;
  const int n0 = rb * 128 + w * 32;

  f16x8 fq[4];
#pragma unroll
  for (int kt = 0; kt < 4; kt++)
    fq[kt] = *reinterpret_cast<const f16x8*>(
        Kfp + ((((n0 >> 5) * 4 + kt) << 9) + (l << 3)));

  auto stage = [&](int bb, int it) {
    if (w < 2) {
      const int mc = 2 * it + w;
#pragma unroll
      for (int c = 0; c < 4; c++)
        gload_lds16(Qfp + (((mc * 4 + c) << 9) + (l << 3)), &kv[bb][w][c][0]);
    } else {
      const int m16 = 4 * it + (w - 2) * 2;
#pragma unroll
      for (int c = 0; c < 4; c++)
        gload_lds16(Vfp + ((((m16 + (c & 1)) * 2 + (c >> 1)) << 9) + (l << 3)),
                    &kv[bb][w][c][0]);
    }
  };
  auto ldfrag = [&](f16x8 (&fr)[4], int bb, int tile) {
#pragma unroll
    for (int c = 0; c < 4; c++)
      fr[c] = *reinterpret_cast<const f16x8*>(&kv[bb][tile][c][l << 3]);
  };

  f32x16 o0 = {}, o1 = {};
  float den[4] = {0.f, 0.f, 0.f, 0.f};
  stage(0, 0);
  asm volatile("s_waitcnt vmcnt(0)" ::: "memory");
  __builtin_amdgcn_s_barrier();
  int cur = 0;
  for (int it = 0; it < SEQ / 64; it++) {
    if (it + 1 < SEQ / 64) stage(cur ^ 1, it + 1);
    f16x8 fkA[4], fvA[4], fkB[4], fvB[4];
    ldfrag(fkA, cur, 0); ldfrag(fvA, cur, 2);
    attn_step(fkA, fvA, fq, o0, o1, den);
    ldfrag(fkB, cur, 1); ldfrag(fvB, cur, 3);
    attn_step(fkB, fvB, fq, o0, o1, den);
    asm volatile("s_waitcnt vmcnt(0)" ::: "memory");
    __builtin_amdgcn_s_barrier();
    cur ^= 1;
  }
  float d = (den[0] + den[1]) + (den[2] + den[3]);
  d += __shfl_xor(d, 32, 64);
  const float inv = SCALE_F / d;
#pragma unroll
  for (int r = 0; r < 16; r++) {
    const int nr = (r & 3) + 8 * (r >> 2) + 4 * hi;
    const float invr = __shfl(inv, nr, 64);
    const size_t row = ((size_t)(b * SEQ + n0 + nr)) * DMODEL + h * HDIM;
    AO[row + ln] = (f16)(o0[r] * invr);
    AO[row + 32 + ln] = (f16)(o1[r] * invr);
  }
}

extern "C" void kernel_launch(void* const* d_in, const int* in_sizes, int n_in,
                              void* d_out, int out_size, void* d_ws, size_t ws_size,
                              hipStream_t stream) {
  const float* x = (const float*)d_in[0];
  const float* Wqkv = (const float*)d_in[1];
  const float* bqkv = (const float*)d_in[2];
  const float* Wproj = (const float*)d_in[3];
  const float* bproj = (const float*)d_in[4];
  float* outp = (float*)d_out;

  // Workspace plan (52.5 MiB; R12-verified). AO aliases xh (dead after
  // gemm<0>); the old 64.5 MiB plan overflowed ws and caused R8-R11 flakes.
  f16* xh = (f16*)d_ws;                                  // [8192][768]
  f16* AO = xh;                                          // alias
  f16* wqkvt = xh + (size_t)NB_TOK * DMODEL;             // [2304][768]
  f16* wprojt = wqkvt + (size_t)QKV3 * DMODEL;           // [768][768]
  f16* Qf = wprojt + (size_t)DMODEL * DMODEL;            // frag layout
  f16* Kf = Qf + (size_t)NBATCH * NHEAD * SEQ * HDIM;
  f16* Vf = Kf + (size_t)NBATCH * NHEAD * SEQ * HDIM;

  prep_k<<<CVT_BLKS + WQKV_TILES + WPROJ_TILES, 256, 0, stream>>>(
      x, xh, Wqkv, wqkvt, Wproj, wprojt);
  gemm128_k<0><<<dim3(QKV3 / 128, NB_TOK / 128), 256, 0, stream>>>(
      xh, wqkvt, bqkv, DMODEL, Qf, Kf, Vf, nullptr);
  attn_k<<<dim3(SEQ / 128, NBATCH * NHEAD), 256, 0, stream>>>(Qf, Kf, Vf, AO);
  gemm128_k<1><<<dim3(DMODEL / 128, NB_TOK / 128), 256, 0, stream>>>(
      AO, wprojt, bproj, DMODEL, nullptr, nullptr, nullptr, outp);
}

// Round 32
// 152.493 us; speedup vs baseline: 1.1135x; 1.0056x over previous
//
#include <hip/hip_runtime.h>
#include <stdint.h>

#define NB_TOK 8192   // B*N
#define DMODEL 768
#define NHEAD 12
#define HDIM 64
#define QKV3 2304
#define SEQ 2048
#define NBATCH 4
#define SCALE_F 0.125f
#define LOG2E 1.44269504f

typedef _Float16 f16;
typedef __attribute__((ext_vector_type(2))) __fp16 hf16x2;   // cvt_pkrtz return type
typedef __attribute__((ext_vector_type(4))) _Float16 f16x4;
typedef __attribute__((ext_vector_type(8))) _Float16 f16x8;
typedef __attribute__((ext_vector_type(4))) float f32x4;
typedef __attribute__((ext_vector_type(16))) float f32x16;

__device__ __forceinline__ void gload_lds16(const void* g, void* l) {
  __builtin_amdgcn_global_load_lds(
      (const __attribute__((address_space(1))) unsigned int*)g,
      (__attribute__((address_space(3))) unsigned int*)l, 16, 0, 0);
}

// bare v_exp_f32 via the intrinsic (R18-verified).
__device__ __forceinline__ float fast_exp2(float x) {
  return __builtin_amdgcn_exp2f(x);
}

// -------- fused prologue: x cvt + LDS-TILED weight transposes, ONE launch ---
// R31-verified. Region switch is block-uniform (syncthreads legal).
#define CVT_BLKS 6144     // 8192*768/1024
#define WQKV_TILES 1728   // (768/32)*(2304/32)
#define WPROJ_TILES 576   // (768/32)*(768/32)
__global__ __launch_bounds__(256) void prep_k(
    const float* __restrict__ x, f16* __restrict__ xh,
    const float* __restrict__ Wqkv, f16* __restrict__ wqkvt,
    const float* __restrict__ Wproj, f16* __restrict__ wprojt) {
  __shared__ float tile[32][33];
  const int bid = blockIdx.x;
  if (bid < CVT_BLKS) {
    const int i = (bid * 256 + threadIdx.x) * 4;
    const float4 v = *reinterpret_cast<const float4*>(x + i);
    f16x4 o;
    o[0] = (f16)v.x; o[1] = (f16)v.y; o[2] = (f16)v.z; o[3] = (f16)v.w;
    *reinterpret_cast<f16x4*>(xh + i) = o;
  } else if (bid < CVT_BLKS + WQKV_TILES) {
    // wqkvt[c][r] = Wqkv[r][c]; R=768 rows, C=2304 cols; 32x32 tile per block
    const int t = bid - CVT_BLKS;
    const int ntc = QKV3 / 32;                       // 72 tiles along C
    const int tr = t / ntc, tc = t - tr * ntc;
    const int tx = threadIdx.x & 31, ty = threadIdx.x >> 5;   // 32x8
#pragma unroll
    for (int i = 0; i < 4; i++)
      tile[ty + i * 8][tx] =
          Wqkv[(size_t)(tr * 32 + ty + i * 8) * QKV3 + tc * 32 + tx];
    __syncthreads();
#pragma unroll
    for (int i = 0; i < 4; i++)
      wqkvt[(size_t)(tc * 32 + ty + i * 8) * DMODEL + tr * 32 + tx] =
          (f16)tile[tx][ty + i * 8];
  } else {
    // wprojt[c][r] = Wproj[r][c]; R=C=768
    const int t = bid - CVT_BLKS - WQKV_TILES;
    const int ntc = DMODEL / 32;                     // 24 tiles along C
    const int tr = t / ntc, tc = t - tr * ntc;
    const int tx = threadIdx.x & 31, ty = threadIdx.x >> 5;
#pragma unroll
    for (int i = 0; i < 4; i++)
      tile[ty + i * 8][tx] =
          Wproj[(size_t)(tr * 32 + ty + i * 8) * DMODEL + tc * 32 + tx];
    __syncthreads();
#pragma unroll
    for (int i = 0; i < 4; i++)
      wprojt[(size_t)(tc * 32 + ty + i * 8) * DMODEL + tr * 32 + tx] =
          (f16)tile[tx][ty + i * 8];
  }
}

// --- 128x128 MFMA GEMM, BK=32, 4 waves, 2-DEEP pipeline + XCD swizzle ------
// R22-VERIFIED (session best). MODE 0 epilogue writes Q/K/V in MFMA-FRAGMENT
// layout; K PRE-SCALED by LOG2E so attention uses exp2 directly.
template <int MODE>
__global__ __launch_bounds__(256) void gemm128_k(
    const f16* __restrict__ A, const f16* __restrict__ Bt,
    const float* __restrict__ bias, int K,
    f16* __restrict__ Qf, f16* __restrict__ Kf, f16* __restrict__ Vf,
    float* __restrict__ Of) {
  __shared__ __align__(16) f16 As[3][128 * 32];
  __shared__ __align__(16) f16 Bs[3][128 * 32];
  const int tid = threadIdx.x;
  const int w = tid >> 6, l = tid & 63;
  const int lr = l >> 2, lc = l & 3;
  const int nwg = gridDim.x * gridDim.y;
  const int lid = blockIdx.y * gridDim.x + blockIdx.x;
  const int wg = (lid & 7) * (nwg >> 3) + (lid >> 3);
  const int bm = (wg / gridDim.x) * 128, bn = (wg % gridDim.x) * 128;
  const f16* ga = A + (size_t)(bm + lr) * K + lc * 8;
  const f16* gb = Bt + (size_t)(bn + lr) * K + lc * 8;
  const int wr = (w >> 1) * 64, wc = (w & 1) * 64;
  const int fr = l & 15, fk = (l >> 4) * 8;

  auto stage = [&](int bb, int kt) {
    gload_lds16(ga + (size_t)(w * 16) * K + kt, &As[bb][(w * 16) * 32]);
    gload_lds16(ga + (size_t)((w + 4) * 16) * K + kt, &As[bb][((w + 4) * 16) * 32]);
    gload_lds16(gb + (size_t)(w * 16) * K + kt, &Bs[bb][(w * 16) * 32]);
    gload_lds16(gb + (size_t)((w + 4) * 16) * K + kt, &Bs[bb][((w + 4) * 16) * 32]);
  };

  f32x4 acc[4][4] = {};
  stage(0, 0);
  if (32 < K) stage(1, 32);
  int cur = 0;
  for (int kt = 0; kt < K; kt += 32) {
    if (kt + 64 < K) stage((cur + 2) % 3, kt + 64);
    if (kt + 64 < K)      asm volatile("s_waitcnt vmcnt(8)" ::: "memory");
    else if (kt + 32 < K) asm volatile("s_waitcnt vmcnt(4)" ::: "memory");
    else                  asm volatile("s_waitcnt vmcnt(0)" ::: "memory");
    __builtin_amdgcn_s_barrier();
    f16x8 af[4], bfrag[4];
#pragma unroll
    for (int mi = 0; mi < 4; mi++)
      af[mi] = *reinterpret_cast<const f16x8*>(&As[cur][(wr + mi * 16 + fr) * 32 + fk]);
#pragma unroll
    for (int ni = 0; ni < 4; ni++)
      bfrag[ni] = *reinterpret_cast<const f16x8*>(&Bs[cur][(wc + ni * 16 + fr) * 32 + fk]);
#pragma unroll
    for (int mi = 0; mi < 4; mi++)
#pragma unroll
      for (int ni = 0; ni < 4; ni++)
        acc[mi][ni] = __builtin_amdgcn_mfma_f32_16x16x32_f16(af[mi], bfrag[ni],
                                                             acc[mi][ni], 0, 0, 0);
    __builtin_amdgcn_s_barrier();
    cur = (cur + 1) % 3;
  }
  const int rgrp = (l >> 4) * 4;
#pragma unroll
  for (int ni = 0; ni < 4; ni++) {
    const int j = bn + wc + ni * 16 + fr;
    const float bb = bias[j];
    if (MODE == 0) {
      const int s = j / DMODEL;            // 0=Q 1=K 2=V, uniform per block
      const int rem = j - s * DMODEL;
      const int h = rem >> 6, hd = rem & 63;
      f16* dqk = (s == 0) ? Qf : Kf;
      const float scale = (s == 1) ? LOG2E : 1.0f;   // K pre-scaled for exp2
#pragma unroll
      for (int mi = 0; mi < 4; mi++)
#pragma unroll
        for (int r = 0; r < 4; r++) {
          const int m = bm + wr + mi * 16 + rgrp + r;   // global token
          const int bidx = m >> 11, n2 = m & 2047;      // batch, token-in-seq
          const f16 hv = (f16)((acc[mi][ni][r] + bb) * scale);
          const size_t bbase = (size_t)(bidx * NHEAD + h) * (SEQ * HDIM);
          if (s < 2) {
            const int mc = n2 >> 5, kt = hd >> 4;
            const int lane = (n2 & 31) + ((hd >> 3) & 1) * 32;
            dqk[bbase + (size_t)(((mc * 4 + kt) << 9) + (lane << 3) + (hd & 7))] = hv;
          } else {
            const int mc16 = n2 >> 4, g = hd >> 5;
            const int lane = (hd & 31) + ((n2 >> 3) & 1) * 32;
            Vf[bbase + (size_t)((((mc16 << 1) + g) << 9) + (lane << 3) + (n2 & 7))] = hv;
          }
        }
    } else {
#pragma unroll
      for (int mi = 0; mi < 4; mi++)
#pragma unroll
        for (int r = 0; r < 4; r++) {
          const int m = bm + wr + mi * 16 + rgrp + r;
          Of[(size_t)m * DMODEL + j] = acc[mi][ni][r] + bb;
        }
    }
  }
}

// ---------------- fused attention: LDS-staged shared K/V fragments ----------
// R22-VERIFIED. Three independent attn-structure modifications (R15 dacc,
// R24 tri-buffer, R26 dual-set) each failed correctness despite paper-proofs;
// this exact structure is the keeper.
__device__ __forceinline__ void attn_step(const f16x8 (&fk)[4], const f16x8 (&fv)[4],
                                          const f16x8 (&fq)[4], f32x16& o0, f32x16& o1,
                                          float (&den)[4]) {
  f32x16 acc;
#pragma unroll
  for (int r = 0; r < 16; r++) acc[r] = -12.0f;   // folds the 2^-12 P-scale
#pragma unroll
  for (int kt = 0; kt < 4; kt++)
    acc = __builtin_amdgcn_mfma_f32_32x32x16_f16(fk[kt], fq[kt], acc, 0, 0, 0);
  float p[16];
#pragma unroll
  for (int r = 0; r < 16; r++) {
    p[r] = fast_exp2(acc[r]);   // = exp(s)*2^-12 (K pre-scaled by log2e)
    den[r & 3] += p[r];
  }
  union PW { hf16x2 h; uint32_t w; };
  uint32_t u[8];
#pragma unroll
  for (int i = 0; i < 8; i++) {
    PW t; t.h = __builtin_amdgcn_cvt_pkrtz(p[2 * i], p[2 * i + 1]);
    u[i] = t.w;
  }
  asm("v_permlane32_swap_b32 %0, %1" : "+v"(u[0]), "+v"(u[2]));
  asm("v_permlane32_swap_b32 %0, %1" : "+v"(u[1]), "+v"(u[3]));
  asm("v_permlane32_swap_b32 %0, %1" : "+v"(u[4]), "+v"(u[6]));
  asm("v_permlane32_swap_b32 %0, %1" : "+v"(u[5]), "+v"(u[7]));
  union FR { uint32_t w[4]; f16x8 v; };
  FR fa0, fa1;
  fa0.w[0] = u[0]; fa0.w[1] = u[1]; fa0.w[2] = u[2]; fa0.w[3] = u[3];
  fa1.w[0] = u[4]; fa1.w[1] = u[5]; fa1.w[2] = u[6]; fa1.w[3] = u[7];
  o0 = __builtin_amdgcn_mfma_f32_32x32x16_f16(fa0.v, fv[0], o0, 0, 0, 0);
  o0 = __builtin_amdgcn_mfma_f32_32x32x16_f16(fa1.v, fv[1], o0, 0, 0, 0);
  o1 = __builtin_amdgcn_mfma_f32_32x32x16_f16(fa0.v, fv[2], o1, 0, 0, 0);
  o1 = __builtin_amdgcn_mfma_f32_32x32x16_f16(fa1.v, fv[3], o1, 0, 0, 0);
}

__global__ __launch_bounds__(256, 3) void attn_k(const f16* __restrict__ Qf,
                                                 const f16* __restrict__ Kf,
                                                 const f16* __restrict__ Vf,
                                                 f16* __restrict__ AO) {
  // [buf][tile: 0=fkA 1=fkB 2=fvA 3=fvB][chunk][512 halfs] = 32 KB
  __shared__ __align__(16) f16 kv[2][4][4][512];
  // XCD-chunked bijective swizzle (768 = 8 XCDs x 96), R19-verified.
  const int lid = blockIdx.y * 16 + blockIdx.x;
  const int wg = (lid & 7) * 96 + (lid >> 3);
  const int rb = wg & 15;
  const int bh = wg >> 4;
  const int b = bh / NHEAD, h = bh - b * NHEAD;
  const int w = threadIdx.x >> 6, l = threadIdx.x & 63;
  const int ln = l & 31, hi = l >> 5;
  const size_t base = (size_t)bh * SEQ * HDIM;
  const f16* Qfp = Qf + base;
  const f16* Kfp = Kf + base;
  const f16* Vfp = Vf + base;
  const int n0 = rb * 128 + w * 32;

  f16x8 fq[4];
#pragma unroll
  for (int kt = 0; kt < 4; kt++)
    fq[kt] = *reinterpret_cast<const f16x8*>(
        Kfp + ((((n0 >> 5) * 4 + kt) << 9) + (l << 3)));

  auto stage = [&](int bb, int it) {
    if (w < 2) {
      const int mc = 2 * it + w;
#pragma unroll
      for (int c = 0; c < 4; c++)
        gload_lds16(Qfp + (((mc * 4 + c) << 9) + (l << 3)), &kv[bb][w][c][0]);
    } else {
      const int m16 = 4 * it + (w - 2) * 2;
#pragma unroll
      for (int c = 0; c < 4; c++)
        gload_lds16(Vfp + ((((m16 + (c & 1)) * 2 + (c >> 1)) << 9) + (l << 3)),
                    &kv[bb][w][c][0]);
    }
  };
  auto ldfrag = [&](f16x8 (&fr)[4], int bb, int tile) {
#pragma unroll
    for (int c = 0; c < 4; c++)
      fr[c] = *reinterpret_cast<const f16x8*>(&kv[bb][tile][c][l << 3]);
  };

  f32x16 o0 = {}, o1 = {};
  float den[4] = {0.f, 0.f, 0.f, 0.f};
  stage(0, 0);
  asm volatile("s_waitcnt vmcnt(0)" ::: "memory");
  __builtin_amdgcn_s_barrier();
  int cur = 0;
  for (int it = 0; it < SEQ / 64; it++) {
    if (it + 1 < SEQ / 64) stage(cur ^ 1, it + 1);
    f16x8 fkA[4], fvA[4], fkB[4], fvB[4];
    ldfrag(fkA, cur, 0); ldfrag(fvA, cur, 2);
    attn_step(fkA, fvA, fq, o0, o1, den);
    ldfrag(fkB, cur, 1); ldfrag(fvB, cur, 3);
    attn_step(fkB, fvB, fq, o0, o1, den);
    asm volatile("s_waitcnt vmcnt(0)" ::: "memory");
    __builtin_amdgcn_s_barrier();
    cur ^= 1;
  }
  float d = (den[0] + den[1]) + (den[2] + den[3]);
  d += __shfl_xor(d, 32, 64);
  const float inv = SCALE_F / d;
#pragma unroll
  for (int r = 0; r < 16; r++) {
    const int nr = (r & 3) + 8 * (r >> 2) + 4 * hi;
    const float invr = __shfl(inv, nr, 64);
    const size_t row = ((size_t)(b * SEQ + n0 + nr)) * DMODEL + h * HDIM;
    AO[row + ln] = (f16)(o0[r] * invr);
    AO[row + 32 + ln] = (f16)(o1[r] * invr);
  }
}

extern "C" void kernel_launch(void* const* d_in, const int* in_sizes, int n_in,
                              void* d_out, int out_size, void* d_ws, size_t ws_size,
                              hipStream_t stream) {
  const float* x = (const float*)d_in[0];
  const float* Wqkv = (const float*)d_in[1];
  const float* bqkv = (const float*)d_in[2];
  const float* Wproj = (const float*)d_in[3];
  const float* bproj = (const float*)d_in[4];
  float* outp = (float*)d_out;

  // Workspace plan (52.5 MiB; R12-verified). AO aliases xh (dead after
  // gemm<0>); the old 64.5 MiB plan overflowed ws and caused R8-R11 flakes.
  f16* xh = (f16*)d_ws;                                  // [8192][768]
  f16* AO = xh;                                          // alias
  f16* wqkvt = xh + (size_t)NB_TOK * DMODEL;             // [2304][768]
  f16* wprojt = wqkvt + (size_t)QKV3 * DMODEL;           // [768][768]
  f16* Qf = wprojt + (size_t)DMODEL * DMODEL;            // frag layout
  f16* Kf = Qf + (size_t)NBATCH * NHEAD * SEQ * HDIM;
  f16* Vf = Kf + (size_t)NBATCH * NHEAD * SEQ * HDIM;

  prep_k<<<CVT_BLKS + WQKV_TILES + WPROJ_TILES, 256, 0, stream>>>(
      x, xh, Wqkv, wqkvt, Wproj, wprojt);
  gemm128_k<0><<<dim3(QKV3 / 128, NB_TOK / 128), 256, 0, stream>>>(
      xh, wqkvt, bqkv, DMODEL, Qf, Kf, Vf, nullptr);
  attn_k<<<dim3(SEQ / 128, NBATCH * NHEAD), 256, 0, stream>>>(Qf, Kf, Vf, AO);
  gemm128_k<1><<<dim3(DMODEL / 128, NB_TOK / 128), 256, 0, stream>>>(
      AO, wprojt, bproj, DMODEL, nullptr, nullptr, nullptr, outp);
}